// Round 3
// baseline (354.021 us; speedup 1.0000x reference)
//
#include <hip/hip_runtime.h>
#include <math.h>

#define DD 128
#define KK 8
#define LN_EPS 1e-5f
#define NORM_EPS 1e-12f

typedef __attribute__((ext_vector_type(8))) short bf16x8;
typedef __attribute__((ext_vector_type(16))) float f32x16;
typedef unsigned int uint;
typedef unsigned short ushort;

// ws layout (bytes):
//   [0, 122880)        wsA: packed bf16 A-frags of W_ext (160x128):
//                      [split(3)][jt(5)][ks(8)][lane(64)][8 bf16]
//   [122880, 123904)   g2b: 128 x {gamma^2, bias} float2
//   [123904, 124032)   scal[32]: 0..7 pk, 8..15 q0k, 16 cg2s, 17 cgbs,
//                      18 cb2s, 19 cs1, 20 ct1, 21 cr1, 22..29 cuk
#define G2B_OFF_F   (122880 / 4)
#define SCAL_OFF_F  (123904 / 4)

// exact 3-way bf16 split with RNE (prep only)
__device__ inline void split3(float x, uint& h, uint& m, uint& l) {
    uint u0 = __float_as_uint(x);
    uint rh = (u0 + 0x7FFFu + ((u0 >> 16) & 1u)) & 0xFFFF0000u;
    float xh = __uint_as_float(rh);
    float r1 = x - xh;
    uint u1 = __float_as_uint(r1);
    uint rm = (u1 + 0x7FFFu + ((u1 >> 16) & 1u)) & 0xFFFF0000u;
    float xm = __uint_as_float(rm);
    float r2 = r1 - xm;
    uint u2 = __float_as_uint(r2);
    uint rl = (u2 + 0x7FFFu + ((u2 >> 16) & 1u));
    h = rh; m = rm; l = rl;
}

// cheap truncating 3-way split (main loop); residuals exact, last limb trunc.
__device__ inline void split3t(float x, uint& h, uint& m, uint& l) {
    uint u0 = __float_as_uint(x);
    float xh = __uint_as_float(u0 & 0xFFFF0000u);
    float r1 = x - xh;
    uint u1 = __float_as_uint(r1);
    float xm = __uint_as_float(u1 & 0xFFFF0000u);
    float r2 = r1 - xm;
    h = u0; m = u1; l = __float_as_uint(r2);
}

__device__ inline uint packhi(uint a1, uint a0) {
    return __builtin_amdgcn_perm(a1, a0, 0x07060302u);
}

__device__ inline void split2packt(float e0, float e1, uint& ph, uint& pm, uint& pl) {
    uint h0, m0, l0, h1, m1, l1;
    split3t(e0, h0, m0, l0);
    split3t(e1, h1, m1, l1);
    ph = packhi(h1, h0);
    pm = packhi(m1, m0);
    pl = packhi(l1, l0);
}

union FragU  { uint4 u; bf16x8 f; };
union AccU16 { f32x16 v; float a[16]; };

// ---------------------------------------------------------------------------
// prep0: scalar tables (1 block x 128 threads)
// ---------------------------------------------------------------------------
__global__ void l1q_prep0(const float* __restrict__ b, const float* __restrict__ gamma,
                          const float* __restrict__ beta, const float* __restrict__ cb,
                          float* __restrict__ ws)
{
    __shared__ float invn_s[KK];
    const int t = threadIdx.x;  // 128
    if (t < KK) {
        float s = 0.f;
        for (int j = 0; j < DD; ++j) { float v = cb[t * DD + j]; s = fmaf(v, v, s); }
        invn_s[t] = 1.0f / fmaxf(sqrtf(s), NORM_EPS);
    }
    __syncthreads();
    {
        float g = gamma[t];
        float* g2b = ws + G2B_OFF_F;
        g2b[2 * t]     = g * g;
        g2b[2 * t + 1] = b[t];
    }
    float* scal = ws + SCAL_OFF_F;
    if (t < KK) {
        float in = invn_s[t];
        float p = 0.f, q = 0.f, cu = 0.f;
        for (int j = 0; j < DD; ++j) {
            float c = cb[t * DD + j] * in;
            p  = fmaf(c, gamma[j], p);
            q  = fmaf(c, beta[j], q);
            cu = fmaf(c * gamma[j], b[j], cu);
        }
        scal[t]      = p;   // pk
        scal[8 + t]  = q;   // q0k
        scal[22 + t] = cu;  // cuk
    }
    if (t == 16) { float s = 0.f; for (int j = 0; j < DD; ++j) { float g = gamma[j]; s = fmaf(g, g, s); } scal[16] = s; }
    if (t == 17) { float s = 0.f; for (int j = 0; j < DD; ++j) s = fmaf(gamma[j], beta[j], s); scal[17] = s; }
    if (t == 18) { float s = 0.f; for (int j = 0; j < DD; ++j) { float v = beta[j]; s = fmaf(v, v, s); } scal[18] = s; }
    if (t == 19) { float s = 0.f; for (int j = 0; j < DD; ++j) s += b[j]; scal[19] = s; }                        // cs1
    if (t == 20) { float s = 0.f; for (int j = 0; j < DD; ++j) s = fmaf(gamma[j] * gamma[j], b[j], s); scal[20] = s; } // ct1
    if (t == 21) { float s = 0.f; for (int j = 0; j < DD; ++j) s = fmaf(gamma[j] * beta[j], b[j], s); scal[21] = s; }  // cr1
}

// ---------------------------------------------------------------------------
// prepA: build W_ext (160x128: 128 W rows + 11 folded + 21 zero), 3-way split,
// pack into 32x32x16 MFMA A-frag layout. grid 40 blocks: bid -> (jt, ks).
// A-frag: lane = m_local + 32*(k_local>>3), elem i = k_local&7.
// ---------------------------------------------------------------------------
__global__ void l1q_prepA(const float* __restrict__ W, const float* __restrict__ b,
                          const float* __restrict__ gamma, const float* __restrict__ beta,
                          const float* __restrict__ cb, ushort* __restrict__ wsA)
{
    __shared__ float invn_s[KK];
    __shared__ float we[11][DD];
    __shared__ float wext[32][16];
    const int t = threadIdx.x;          // 256
    const int jt = blockIdx.x >> 3;     // 0..4
    const int ks = blockIdx.x & 7;      // 0..7

    if (jt == 4) {
        if (t < KK) {
            float s = 0.f;
            for (int j = 0; j < DD; ++j) { float v = cb[t * DD + j]; s = fmaf(v, v, s); }
            invn_s[t] = 1.0f / fmaxf(sqrtf(s), NORM_EPS);
        }
        __syncthreads();
        for (int idx = t; idx < 11 * DD; idx += 256) {
            int e = idx / DD, j = idx % DD;
            float g = gamma[j];
            float v;
            if (e == 0)      v = 1.0f;
            else if (e == 1) v = g * g;
            else if (e == 2) v = g * beta[j];
            else             v = cb[(e - 3) * DD + j] * invn_s[e - 3] * g;
            we[e][j] = v;
        }
        __syncthreads();
    }

    for (int idx = t; idx < 512; idx += 256) {
        int jl = idx >> 4, kk = idx & 15;
        int k = ks * 16 + kk;
        float val;
        if (jt < 4) {
            val = W[(jt * 32 + jl) * DD + k];
        } else if (jl < 11) {
            float s = 0.f;
            for (int j = 0; j < DD; ++j) s = fmaf(we[jl][j], W[j * DD + k], s);
            val = s;
        } else {
            val = 0.f;
        }
        wext[jl][kk] = val;
    }
    __syncthreads();

    for (int idx = t; idx < 512; idx += 256) {
        int jl = idx >> 4, kk = idx & 15;
        int lane = jl + 32 * (kk >> 3);
        int i = kk & 7;
        uint h, m, l;
        split3(wext[jl][kk], h, m, l);
        int base = jt * 8 + ks;
        wsA[(0 * 40 + base) * 512 + lane * 8 + i] = (ushort)(h >> 16);
        wsA[(1 * 40 + base) * 512 + lane * 8 + i] = (ushort)(m >> 16);
        wsA[(2 * 40 + base) * 512 + lane * 8 + i] = (ushort)(l >> 16);
    }
}

// ---------------------------------------------------------------------------
// main: grid = B/1024 = 256 blocks (1/CU), 1024 threads = 16 waves.
// Single 120 KB W-frag preload per block, then 2 chunks of 512 rows.
// x is read as one DENSE per-chunk burst (16 dwordx4/lane covering the full
// 512 B row; wave-dense 16 KB) into registers -- one DRAM page activation per
// page instead of 8 with the old 64B/512B-strided per-ks pattern. The ks loop
// has NO loads. Chunk 1's burst is issued after chunk 0's MFMA loop and
// BEFORE the epilogue stores, so its (in-order) vmcnt decrements never queue
// behind the store drain, and the burst overlaps epilogue compute.
// D[j_ext][n] = W_ext x x^T via 6-product split-bf16 mfma_32x32x16.
// Lane: n = lane&31 (x-row), h = lane>>5 (k-half). C/D row = (reg&3)+8*(reg>>2)+4*h.
// ---------------------------------------------------------------------------
__global__ __launch_bounds__(1024, 4)
void l1q_main(const float* __restrict__ x, const ushort* __restrict__ wsA,
              const float* __restrict__ wsf, const float* __restrict__ cb,
              float* __restrict__ out_idx, float* __restrict__ out_soft,
              float* __restrict__ out_emb, float* __restrict__ out_log,
              int B)
{
    __shared__ uint4 Wl4[7680];        // 122880 B packed W_ext frags
    __shared__ float gath[16][352];    // [wave][n*11 + local], gcd(11,32)=1
    __shared__ int   besti[16][32];
    __shared__ float g2b_s[256];
    __shared__ float scal_s[32];

    const int t = threadIdx.x;
    const int wave = t >> 6;
    const int lane = t & 63;
    const int n = lane & 31;
    const int h = lane >> 5;

    const float* xp = x + (size_t)(blockIdx.x * 1024 + wave * 32 + n) * DD + h * 8;

    {
        const uint4* src = (const uint4*)wsA;
        #pragma unroll
        for (int i = 0; i < 8; ++i) {
            int idx = t + i * 1024;
            if (idx < 7680) Wl4[idx] = src[idx];
        }
    }
    if (t < 256) g2b_s[t] = wsf[G2B_OFF_F + t];
    if (t < 32)  scal_s[t] = wsf[SCAL_OFF_F + t];
    __syncthreads();

    // dense burst: chunk 0's full x rows into registers (after the barrier --
    // a pre-barrier burst would serialize into the barrier's vmcnt(0) drain)
    float4 xa[8], xc[8];
    #pragma unroll
    for (int ks = 0; ks < 8; ++ks) {
        xa[ks] = *(const float4*)(xp + ks * 16);
        xc[ks] = *(const float4*)(xp + ks * 16 + 4);
    }

    const float inv128 = 1.0f / 128.0f;

    #pragma unroll 1
    for (int c = 0; c < 2; ++c) {
        const int rowbase = blockIdx.x * 1024 + c * 512 + wave * 32;

        f32x16 acc[5];
        #pragma unroll
        for (int jt = 0; jt < 5; ++jt)
            #pragma unroll
            for (int r = 0; r < 16; ++r) acc[jt][r] = 0.f;

        #pragma unroll
        for (int ks = 0; ks < 8; ++ks) {
            FragU xh, xm, xl;
            split2packt(xa[ks].x, xa[ks].y, xh.u.x, xm.u.x, xl.u.x);
            split2packt(xa[ks].z, xa[ks].w, xh.u.y, xm.u.y, xl.u.y);
            split2packt(xc[ks].x, xc[ks].y, xh.u.z, xm.u.z, xl.u.z);
            split2packt(xc[ks].z, xc[ks].w, xh.u.w, xm.u.w, xl.u.w);

            #pragma unroll
            for (int jt = 0; jt < 5; ++jt) {
                const int pl = jt * 8 + ks;
                FragU wh, wm, wl;
                wh.u = Wl4[(0 * 40 + pl) * 64 + lane];
                wm.u = Wl4[(1 * 40 + pl) * 64 + lane];
                wl.u = Wl4[(2 * 40 + pl) * 64 + lane];
                f32x16 cacc = acc[jt];
                cacc = __builtin_amdgcn_mfma_f32_32x32x16_bf16(wl.f, xh.f, cacc, 0, 0, 0);
                cacc = __builtin_amdgcn_mfma_f32_32x32x16_bf16(wh.f, xl.f, cacc, 0, 0, 0);
                cacc = __builtin_amdgcn_mfma_f32_32x32x16_bf16(wm.f, xm.f, cacc, 0, 0, 0);
                cacc = __builtin_amdgcn_mfma_f32_32x32x16_bf16(wm.f, xh.f, cacc, 0, 0, 0);
                cacc = __builtin_amdgcn_mfma_f32_32x32x16_bf16(wh.f, xm.f, cacc, 0, 0, 0);
                cacc = __builtin_amdgcn_mfma_f32_32x32x16_bf16(wh.f, xh.f, cacc, 0, 0, 0);
                acc[jt] = cacc;
            }
        }

        // dense burst for chunk 1, issued BEFORE the epilogue stores so the
        // loads sit ahead of the stores in the in-order vmcnt queue
        if (c == 0) {
            const float* xq = xp + 512 * DD;
            #pragma unroll
            for (int ks = 0; ks < 8; ++ks) {
                xa[ks] = *(const float4*)(xq + ks * 16);
                xc[ks] = *(const float4*)(xq + ks * 16 + 4);
            }
        }

        // ---- quadratic sums over true W rows (jt 0..3) ----
        float s2a = 0.f, t2a = 0.f;
        #pragma unroll
        for (int jt = 0; jt < 4; ++jt) {
            AccU16 a; a.v = acc[jt];
            #pragma unroll
            for (int rq = 0; rq < 4; ++rq) {
                int jb = jt * 32 + 8 * rq + 4 * h;
                #pragma unroll
                for (int r = 0; r < 4; ++r) {
                    float2 gb = *(const float2*)&g2b_s[2 * (jb + r)];
                    float hv = a.a[rq * 4 + r] + gb.y;
                    float h2 = hv * hv;
                    s2a += h2;
                    t2a = fmaf(gb.x, h2, t2a);
                }
            }
        }
        s2a += __shfl_xor(s2a, 32);
        t2a += __shfl_xor(t2a, 32);

        // ---- gather 11 folded linear sums (tile jt=4, locals 0..10) ----
        {
            AccU16 a; a.v = acc[4];
            #pragma unroll
            for (int rq = 0; rq < 4; ++rq) {
                #pragma unroll
                for (int r = 0; r < 4; ++r) {
                    int local = r + 8 * rq + 4 * h;
                    if (local < 11) gath[wave][n * 11 + local] = a.a[rq * 4 + r];
                }
            }
        }
        // lgkmcnt(0) only (vmcnt=63, expcnt=7): wave-internal LDS ordering
        // without draining the in-flight chunk-1 burst
        __builtin_amdgcn_s_waitcnt(0xc07f);
        const float* gp = &gath[wave][n * 11];

        const float cg2s = scal_s[16], cgbs = scal_s[17], cb2s = scal_s[18];

        float s1  = gp[0] + scal_s[19];
        float t1  = gp[1] + scal_s[20];
        float r1v = gp[2] + scal_s[21];
        float u[KK];
        #pragma unroll
        for (int k = 0; k < KK; ++k) u[k] = gp[3 + k] + scal_s[22 + k];

        float mu = s1 * inv128;
        float var = fmaf(-mu, mu, s2a * inv128);
        float istd = 1.0f / sqrtf(var + LN_EPS);
        float nrm2 = istd * istd * (t2a - 2.f * mu * t1 + mu * mu * cg2s)
                   + 2.f * istd * (r1v - mu * cgbs) + cb2s;
        float rinv = 1.0f / fmaxf(sqrtf(fmaxf(nrm2, 0.f)), NORM_EPS);

        float lg[KK];
        #pragma unroll
        for (int k = 0; k < KK; ++k)
            lg[k] = (istd * (u[k] - mu * scal_s[k]) + scal_s[8 + k]) * rinv;

        float mx = lg[0]; int bi = 0;
        #pragma unroll
        for (int k = 1; k < KK; ++k) if (lg[k] > mx) { mx = lg[k]; bi = k; }

        float ex[KK], se = 0.f;
        #pragma unroll
        for (int k = 0; k < KK; ++k) { ex[k] = expf(lg[k] - mx); se += ex[k]; }
        float rse = 1.0f / se;

        const int m = rowbase + n;
        if (h == 0) {
            out_idx[m] = (float)bi;
            besti[wave][n] = bi;
            *(float4*)&out_log[(size_t)m * KK]     = make_float4(lg[0], lg[1], lg[2], lg[3]);
            *(float4*)&out_log[(size_t)m * KK + 4] = make_float4(lg[4], lg[5], lg[6], lg[7]);
        } else {
            *(float4*)&out_soft[(size_t)m * KK]     = make_float4(ex[0] * rse, ex[1] * rse, ex[2] * rse, ex[3] * rse);
            *(float4*)&out_soft[(size_t)m * KK + 4] = make_float4(ex[4] * rse, ex[5] * rse, ex[6] * rse, ex[7] * rse);
        }

        // ---- embedding: emb[row] = codebook[best[row]], coalesced per wave ----
        __builtin_amdgcn_s_waitcnt(0xc07f);   // lgkmcnt(0): besti visibility
        const float4* cb4 = (const float4*)cb;
        float4* eo = (float4*)out_emb;
        #pragma unroll
        for (int i = 0; i < 16; ++i) {
            int f4 = lane + 64 * i;          // 0..1023 over 32 rows x 32 float4
            int rl = f4 >> 5;
            int cc = f4 & 31;
            int k0 = besti[wave][rl];
            eo[(size_t)(rowbase + rl) * 32 + cc] = cb4[k0 * 32 + cc];
        }
    }
}

extern "C" void kernel_launch(void* const* d_in, const int* in_sizes, int n_in,
                              void* d_out, int out_size, void* d_ws, size_t ws_size,
                              hipStream_t stream) {
    const float* x     = (const float*)d_in[0];
    const float* W     = (const float*)d_in[1];
    const float* b     = (const float*)d_in[2];
    const float* gamma = (const float*)d_in[3];
    const float* beta  = (const float*)d_in[4];
    const float* cb    = (const float*)d_in[5];
    const int B = in_sizes[0] / DD;

    float*  ws  = (float*)d_ws;
    ushort* wsA = (ushort*)d_ws;

    float* out    = (float*)d_out;
    float* o_idx  = out;
    float* o_soft = out + (size_t)B;
    float* o_emb  = out + (size_t)B * (1 + KK);
    float* o_log  = out + (size_t)B * (1 + KK + DD);

    hipLaunchKernelGGL(l1q_prep0, dim3(1), dim3(128), 0, stream, b, gamma, beta, cb, ws);
    hipLaunchKernelGGL(l1q_prepA, dim3(40), dim3(256), 0, stream, W, b, gamma, beta, cb, wsA);
    const int grid = B / 1024;   // 256 blocks: 1/CU, 2x512-row chunks each
    hipLaunchKernelGGL(l1q_main, dim3(grid), dim3(1024), 0, stream,
                       x, wsA, ws, cb, o_idx, o_soft, o_emb, o_log, B);
}

// Round 4
// 288.266 us; speedup vs baseline: 1.2281x; 1.2281x over previous
//
#include <hip/hip_runtime.h>
#include <math.h>

#define DD 128
#define KK 8
#define LN_EPS 1e-5f
#define NORM_EPS 1e-12f

typedef __attribute__((ext_vector_type(8))) short bf16x8;
typedef __attribute__((ext_vector_type(16))) float f32x16;
typedef unsigned int uint;
typedef unsigned short ushort;

// ws layout (bytes):
//   [0, 122880)        wsA: packed bf16 A-frags of W_ext (160x128):
//                      [split(3)][jt(5)][ks(8)][lane(64)][8 bf16]
//   [122880, 123904)   g2b: 128 x {gamma^2, bias} float2
//   [123904, 124032)   scal[32]: 0..7 pk, 8..15 q0k, 16 cg2s, 17 cgbs,
//                      18 cb2s, 19 cs1, 20 ct1, 21 cr1, 22..29 cuk
#define G2B_OFF_F   (122880 / 4)
#define SCAL_OFF_F  (123904 / 4)

// exact 3-way bf16 split with RNE (prep only)
__device__ inline void split3(float x, uint& h, uint& m, uint& l) {
    uint u0 = __float_as_uint(x);
    uint rh = (u0 + 0x7FFFu + ((u0 >> 16) & 1u)) & 0xFFFF0000u;
    float xh = __uint_as_float(rh);
    float r1 = x - xh;
    uint u1 = __float_as_uint(r1);
    uint rm = (u1 + 0x7FFFu + ((u1 >> 16) & 1u)) & 0xFFFF0000u;
    float xm = __uint_as_float(rm);
    float r2 = r1 - xm;
    uint u2 = __float_as_uint(r2);
    uint rl = (u2 + 0x7FFFu + ((u2 >> 16) & 1u));
    h = rh; m = rm; l = rl;
}

// cheap truncating 3-way split (main loop); residuals exact, last limb trunc.
__device__ inline void split3t(float x, uint& h, uint& m, uint& l) {
    uint u0 = __float_as_uint(x);
    float xh = __uint_as_float(u0 & 0xFFFF0000u);
    float r1 = x - xh;
    uint u1 = __float_as_uint(r1);
    float xm = __uint_as_float(u1 & 0xFFFF0000u);
    float r2 = r1 - xm;
    h = u0; m = u1; l = __float_as_uint(r2);
}

__device__ inline uint packhi(uint a1, uint a0) {
    return __builtin_amdgcn_perm(a1, a0, 0x07060302u);
}

__device__ inline void split2packt(float e0, float e1, uint& ph, uint& pm, uint& pl) {
    uint h0, m0, l0, h1, m1, l1;
    split3t(e0, h0, m0, l0);
    split3t(e1, h1, m1, l1);
    ph = packhi(h1, h0);
    pm = packhi(m1, m0);
    pl = packhi(l1, l0);
}

union FragU  { uint4 u; bf16x8 f; };
union AccU16 { f32x16 v; float a[16]; };

// ---------------------------------------------------------------------------
// prep: build W_ext (160x128: 128 W rows + 11 folded + 21 zero), 3-way split,
// pack into 32x32x16 MFMA A-frag layout. grid 40 blocks: bid -> (jt, ks).
// A-frag: lane = m_local + 32*(k_local>>3), elem i = k_local&7.
// Block (jt=4, ks=0) additionally computes the scalar tables (g2b, scal) --
// the former prep0 kernel, folded here to save one launch round.
// ---------------------------------------------------------------------------
__global__ void l1q_prep(const float* __restrict__ W, const float* __restrict__ b,
                         const float* __restrict__ gamma, const float* __restrict__ beta,
                         const float* __restrict__ cb, ushort* __restrict__ wsA,
                         float* __restrict__ ws)
{
    __shared__ float invn_s[KK];
    __shared__ float we[11][DD];
    __shared__ float wext[32][16];
    const int t = threadIdx.x;          // 256
    const int jt = blockIdx.x >> 3;     // 0..4
    const int ks = blockIdx.x & 7;      // 0..7

    if (jt == 4) {
        if (t < KK) {
            float s = 0.f;
            for (int j = 0; j < DD; ++j) { float v = cb[t * DD + j]; s = fmaf(v, v, s); }
            invn_s[t] = 1.0f / fmaxf(sqrtf(s), NORM_EPS);
        }
        __syncthreads();
        for (int idx = t; idx < 11 * DD; idx += 256) {
            int e = idx / DD, j = idx % DD;
            float g = gamma[j];
            float v;
            if (e == 0)      v = 1.0f;
            else if (e == 1) v = g * g;
            else if (e == 2) v = g * beta[j];
            else             v = cb[(e - 3) * DD + j] * invn_s[e - 3] * g;
            we[e][j] = v;
        }
        __syncthreads();

        if (ks == 0) {                    // former prep0 (scalar tables)
            if (t < DD) {
                float g = gamma[t];
                float* g2b = ws + G2B_OFF_F;
                g2b[2 * t]     = g * g;
                g2b[2 * t + 1] = b[t];
            }
            float* scal = ws + SCAL_OFF_F;
            if (t < KK) {
                float in = invn_s[t];
                float p = 0.f, q = 0.f, cu = 0.f;
                for (int j = 0; j < DD; ++j) {
                    float c = cb[t * DD + j] * in;
                    p  = fmaf(c, gamma[j], p);
                    q  = fmaf(c, beta[j], q);
                    cu = fmaf(c * gamma[j], b[j], cu);
                }
                scal[t]      = p;   // pk
                scal[8 + t]  = q;   // q0k
                scal[22 + t] = cu;  // cuk
            }
            if (t == 16) { float s = 0.f; for (int j = 0; j < DD; ++j) { float g = gamma[j]; s = fmaf(g, g, s); } scal[16] = s; }
            if (t == 17) { float s = 0.f; for (int j = 0; j < DD; ++j) s = fmaf(gamma[j], beta[j], s); scal[17] = s; }
            if (t == 18) { float s = 0.f; for (int j = 0; j < DD; ++j) { float v = beta[j]; s = fmaf(v, v, s); } scal[18] = s; }
            if (t == 19) { float s = 0.f; for (int j = 0; j < DD; ++j) s += b[j]; scal[19] = s; }                              // cs1
            if (t == 20) { float s = 0.f; for (int j = 0; j < DD; ++j) s = fmaf(gamma[j] * gamma[j], b[j], s); scal[20] = s; } // ct1
            if (t == 21) { float s = 0.f; for (int j = 0; j < DD; ++j) s = fmaf(gamma[j] * beta[j], b[j], s); scal[21] = s; }  // cr1
        }
    }

    for (int idx = t; idx < 512; idx += 256) {
        int jl = idx >> 4, kk = idx & 15;
        int k = ks * 16 + kk;
        float val;
        if (jt < 4) {
            val = W[(jt * 32 + jl) * DD + k];
        } else if (jl < 11) {
            float s = 0.f;
            for (int j = 0; j < DD; ++j) s = fmaf(we[jl][j], W[j * DD + k], s);
            val = s;
        } else {
            val = 0.f;
        }
        wext[jl][kk] = val;
    }
    __syncthreads();

    for (int idx = t; idx < 512; idx += 256) {
        int jl = idx >> 4, kk = idx & 15;
        int lane = jl + 32 * (kk >> 3);
        int i = kk & 7;
        uint h, m, l;
        split3(wext[jl][kk], h, m, l);
        int base = jt * 8 + ks;
        wsA[(0 * 40 + base) * 512 + lane * 8 + i] = (ushort)(h >> 16);
        wsA[(1 * 40 + base) * 512 + lane * 8 + i] = (ushort)(m >> 16);
        wsA[(2 * 40 + base) * 512 + lane * 8 + i] = (ushort)(l >> 16);
    }
}

// ---------------------------------------------------------------------------
// main: 1024 threads = 16 waves, 32 rows/wave, 512 rows/block, grid B/512.
// D[j_ext][n] = W_ext x x^T via 6-product split-bf16 mfma_32x32x16.
// Lane: n = lane&31 (x-row), h = lane>>5 (k-half). C/D row = (reg&3)+8*(reg>>2)+4*h.
// x prefetch is TWO ks-iterations deep (3 rotating reg buffers, <=4 loads in
// flight): load->use distance ~2 iterations (~800-1000 cyc) covers LLC/HBM
// latency that R0's 1-ahead scheme left exposed. ks0/ks1 loads issue before
// the W-preload so they ride under preload+barrier.
// ---------------------------------------------------------------------------
__global__ __launch_bounds__(1024, 4)
void l1q_main(const float* __restrict__ x, const ushort* __restrict__ wsA,
              const float* __restrict__ wsf, const float* __restrict__ cb,
              float* __restrict__ out_idx, float* __restrict__ out_soft,
              float* __restrict__ out_emb, float* __restrict__ out_log,
              int B)
{
    __shared__ uint4 Wl4[7680];        // 122880 B packed W_ext frags
    __shared__ float gath[16][352];    // [wave][n*11 + local], gcd(11,32)=1
    __shared__ int   besti[16][32];
    __shared__ float g2b_s[256];
    __shared__ float scal_s[32];

    const int t = threadIdx.x;
    const int wave = t >> 6;
    const int lane = t & 63;
    const int n = lane & 31;
    const int h = lane >> 5;
    const int rowbase = blockIdx.x * 512 + wave * 32;
    const int row = rowbase + n;

    const float* xp = x + (size_t)row * DD + h * 8;
    // ks=0 and ks=1 buffers issued early: latency hides under W-preload+barrier
    float4 c0a = *(const float4*)(xp + 0);
    float4 c0c = *(const float4*)(xp + 4);
    float4 c1a = *(const float4*)(xp + 16);
    float4 c1c = *(const float4*)(xp + 20);

    {
        const uint4* src = (const uint4*)wsA;
        #pragma unroll
        for (int i = 0; i < 8; ++i) {
            int idx = t + i * 1024;
            if (idx < 7680) Wl4[idx] = src[idx];
        }
    }
    if (t < 256) g2b_s[t] = wsf[G2B_OFF_F + t];
    if (t < 32)  scal_s[t] = wsf[SCAL_OFF_F + t];
    __syncthreads();

    f32x16 acc[5];
    #pragma unroll
    for (int jt = 0; jt < 5; ++jt)
        #pragma unroll
        for (int r = 0; r < 16; ++r) acc[jt][r] = 0.f;

    #pragma unroll
    for (int ks = 0; ks < 8; ++ks) {
        // prefetch ks+2 (2-deep); dead-safe: clamp to ks=7's chunk for tail
        int kp = (ks < 6) ? ks + 2 : 7;
        float4 pa = *(const float4*)(xp + kp * 16 + 0);
        float4 pc = *(const float4*)(xp + kp * 16 + 4);

        FragU xh, xm, xl;
        split2packt(c0a.x, c0a.y, xh.u.x, xm.u.x, xl.u.x);
        split2packt(c0a.z, c0a.w, xh.u.y, xm.u.y, xl.u.y);
        split2packt(c0c.x, c0c.y, xh.u.z, xm.u.z, xl.u.z);
        split2packt(c0c.z, c0c.w, xh.u.w, xm.u.w, xl.u.w);

        #pragma unroll
        for (int jt = 0; jt < 5; ++jt) {
            const int pl = jt * 8 + ks;
            FragU wh, wm, wl;
            wh.u = Wl4[(0 * 40 + pl) * 64 + lane];
            wm.u = Wl4[(1 * 40 + pl) * 64 + lane];
            wl.u = Wl4[(2 * 40 + pl) * 64 + lane];
            f32x16 c = acc[jt];
            c = __builtin_amdgcn_mfma_f32_32x32x16_bf16(wl.f, xh.f, c, 0, 0, 0);
            c = __builtin_amdgcn_mfma_f32_32x32x16_bf16(wh.f, xl.f, c, 0, 0, 0);
            c = __builtin_amdgcn_mfma_f32_32x32x16_bf16(wm.f, xm.f, c, 0, 0, 0);
            c = __builtin_amdgcn_mfma_f32_32x32x16_bf16(wm.f, xh.f, c, 0, 0, 0);
            c = __builtin_amdgcn_mfma_f32_32x32x16_bf16(wh.f, xm.f, c, 0, 0, 0);
            c = __builtin_amdgcn_mfma_f32_32x32x16_bf16(wh.f, xh.f, c, 0, 0, 0);
            acc[jt] = c;
        }
        // rotate: cur <- next, next <- prefetched
        c0a = c1a; c0c = c1c;
        c1a = pa;  c1c = pc;
    }

    // ---- quadratic sums over true W rows (jt 0..3) ----
    float s2a = 0.f, t2a = 0.f;
    #pragma unroll
    for (int jt = 0; jt < 4; ++jt) {
        AccU16 a; a.v = acc[jt];
        #pragma unroll
        for (int rq = 0; rq < 4; ++rq) {
            int jb = jt * 32 + 8 * rq + 4 * h;
            #pragma unroll
            for (int r = 0; r < 4; ++r) {
                float2 gb = *(const float2*)&g2b_s[2 * (jb + r)];
                float hv = a.a[rq * 4 + r] + gb.y;
                float h2 = hv * hv;
                s2a += h2;
                t2a = fmaf(gb.x, h2, t2a);
            }
        }
    }
    s2a += __shfl_xor(s2a, 32);
    t2a += __shfl_xor(t2a, 32);

    // ---- gather 11 folded linear sums (tile jt=4, locals 0..10) ----
    {
        AccU16 a; a.v = acc[4];
        #pragma unroll
        for (int rq = 0; rq < 4; ++rq) {
            #pragma unroll
            for (int r = 0; r < 4; ++r) {
                int local = r + 8 * rq + 4 * h;
                if (local < 11) gath[wave][n * 11 + local] = a.a[rq * 4 + r];
            }
        }
    }
    __builtin_amdgcn_s_waitcnt(0);   // wave-internal LDS ordering
    const float* gp = &gath[wave][n * 11];

    const float inv128 = 1.0f / 128.0f;
    const float cg2s = scal_s[16], cgbs = scal_s[17], cb2s = scal_s[18];

    float s1  = gp[0] + scal_s[19];
    float t1  = gp[1] + scal_s[20];
    float r1v = gp[2] + scal_s[21];
    float u[KK];
    #pragma unroll
    for (int k = 0; k < KK; ++k) u[k] = gp[3 + k] + scal_s[22 + k];

    float mu = s1 * inv128;
    float var = fmaf(-mu, mu, s2a * inv128);
    float istd = 1.0f / sqrtf(var + LN_EPS);
    float nrm2 = istd * istd * (t2a - 2.f * mu * t1 + mu * mu * cg2s)
               + 2.f * istd * (r1v - mu * cgbs) + cb2s;
    float rinv = 1.0f / fmaxf(sqrtf(fmaxf(nrm2, 0.f)), NORM_EPS);

    float lg[KK];
    #pragma unroll
    for (int k = 0; k < KK; ++k)
        lg[k] = (istd * (u[k] - mu * scal_s[k]) + scal_s[8 + k]) * rinv;

    float mx = lg[0]; int bi = 0;
    #pragma unroll
    for (int k = 1; k < KK; ++k) if (lg[k] > mx) { mx = lg[k]; bi = k; }

    float ex[KK], se = 0.f;
    #pragma unroll
    for (int k = 0; k < KK; ++k) { ex[k] = expf(lg[k] - mx); se += ex[k]; }
    float rse = 1.0f / se;

    const int m = rowbase + n;
    if (h == 0) {
        out_idx[m] = (float)bi;
        besti[wave][n] = bi;
        *(float4*)&out_log[(size_t)m * KK]     = make_float4(lg[0], lg[1], lg[2], lg[3]);
        *(float4*)&out_log[(size_t)m * KK + 4] = make_float4(lg[4], lg[5], lg[6], lg[7]);
    } else {
        *(float4*)&out_soft[(size_t)m * KK]     = make_float4(ex[0] * rse, ex[1] * rse, ex[2] * rse, ex[3] * rse);
        *(float4*)&out_soft[(size_t)m * KK + 4] = make_float4(ex[4] * rse, ex[5] * rse, ex[6] * rse, ex[7] * rse);
    }

    // ---- embedding: emb[row] = codebook[best[row]], coalesced per wave ----
    __builtin_amdgcn_s_waitcnt(0);
    const float4* cb4 = (const float4*)cb;
    float4* eo = (float4*)out_emb;
    #pragma unroll
    for (int i = 0; i < 16; ++i) {
        int f4 = lane + 64 * i;          // 0..1023 over 32 rows x 32 float4
        int rl = f4 >> 5;
        int c  = f4 & 31;
        int k0 = besti[wave][rl];
        eo[(size_t)(rowbase + rl) * 32 + c] = cb4[k0 * 32 + c];
    }
}

extern "C" void kernel_launch(void* const* d_in, const int* in_sizes, int n_in,
                              void* d_out, int out_size, void* d_ws, size_t ws_size,
                              hipStream_t stream) {
    const float* x     = (const float*)d_in[0];
    const float* W     = (const float*)d_in[1];
    const float* b     = (const float*)d_in[2];
    const float* gamma = (const float*)d_in[3];
    const float* beta  = (const float*)d_in[4];
    const float* cb    = (const float*)d_in[5];
    const int B = in_sizes[0] / DD;

    float*  ws  = (float*)d_ws;
    ushort* wsA = (ushort*)d_ws;

    float* out    = (float*)d_out;
    float* o_idx  = out;
    float* o_soft = out + (size_t)B;
    float* o_emb  = out + (size_t)B * (1 + KK);
    float* o_log  = out + (size_t)B * (1 + KK + DD);

    hipLaunchKernelGGL(l1q_prep, dim3(40), dim3(256), 0, stream, W, b, gamma, beta, cb, wsA, ws);
    const int grid = B / 512;
    hipLaunchKernelGGL(l1q_main, dim3(grid), dim3(1024), 0, stream,
                       x, wsA, ws, cb, o_idx, o_soft, o_emb, o_log, B);
}